// Round 3
// baseline (341.174 us; speedup 1.0000x reference)
//
#include <hip/hip_runtime.h>
#include <hip/hip_bf16.h>
#include <math.h>

// Problem constants (from reference): B=8, T=1, H=16, DH=256, DMODEL=4096,
// PAST=4096, ROTARY_DIM=64, ROPE_BASE=10000
#define NB 8
#define NH 16
#define DHD 256
#define DM 4096
#define NPAST 4096
#define STOT 4097          // PAST + T
#define NSPLIT 32          // flash-decode splits per (b,h)
#define KPS 129            // ceil(4097/32)

__device__ __forceinline__ float dot4(float4 a, float4 b) {
  return fmaf(a.x, b.x, fmaf(a.y, b.y, fmaf(a.z, b.z, a.w * b.w)));
}

__device__ __forceinline__ float wave_sum(float v) {
#pragma unroll
  for (int off = 32; off > 0; off >>= 1) v += __shfl_xor(v, off, 64);
  return v;
}

// ---------------- kernel 1: fused QKV GEMV, 8 right-hand sides ----------------
// q[b][r] = sum_c Wq[r][c] * hid[b][c]  (and same for k, v)
__global__ __launch_bounds__(256) void k_qkv(const float* __restrict__ hid,
                                             const float* __restrict__ Wq,
                                             const float* __restrict__ Wk,
                                             const float* __restrict__ Wv,
                                             float* __restrict__ qb,
                                             float* __restrict__ kb,
                                             float* __restrict__ vb) {
  const int lane = threadIdx.x & 63;
  const int wid  = threadIdx.x >> 6;
  const int task = blockIdx.x * 4 + wid;      // 0..3071 (3 matrices * 1024 row-groups)
  const int mat  = task >> 10;
  const int r    = (task & 1023) << 2;        // row base (4 rows per wave)
  const float* W = (mat == 0) ? Wq : ((mat == 1) ? Wk : Wv);
  float* out     = (mat == 0) ? qb : ((mat == 1) ? kb : vb);
  const float4* W4 = (const float4*)(W + (size_t)r * DM);
  const float4* h4 = (const float4*)hid;

  float a0[8], a1[8], a2[8], a3[8];
#pragma unroll
  for (int b = 0; b < 8; ++b) a0[b] = a1[b] = a2[b] = a3[b] = 0.f;

  for (int it = 0; it < 16; ++it) {
    const int c4 = it * 64 + lane;            // float4 column index, coalesced
    const float4 w0 = W4[c4];
    const float4 w1 = W4[1024 + c4];
    const float4 w2 = W4[2048 + c4];
    const float4 w3 = W4[3072 + c4];
#pragma unroll
    for (int b = 0; b < 8; ++b) {
      const float4 hv = h4[b * 1024 + c4];
      a0[b] += dot4(w0, hv);
      a1[b] += dot4(w1, hv);
      a2[b] += dot4(w2, hv);
      a3[b] += dot4(w3, hv);
    }
  }
#pragma unroll
  for (int b = 0; b < 8; ++b) {
    const float v0 = wave_sum(a0[b]);
    const float v1 = wave_sum(a1[b]);
    const float v2 = wave_sum(a2[b]);
    const float v3 = wave_sum(a3[b]);
    if (lane == b) {                          // compile-time b -> no scratch
      out[b * DM + r + 0] = v0;
      out[b * DM + r + 1] = v1;
      out[b * DM + r + 2] = v2;
      out[b * DM + r + 3] = v3;
    }
  }
}

// ---------------- kernel 2: GPT-J RoPE on q and k (first 64 dims/head) --------
// pairs (2i, 2i+1): out[2i] = x1*c - x2*s ; out[2i+1] = x2*c + x1*s
// position_ids: declared int64 in the reference, but JAX without x64 silently
// stores int32 -> read as int32.
__global__ void k_rope(float* __restrict__ qb, float* __restrict__ kb,
                       const int* __restrict__ pos) {
  const int id = blockIdx.x * 256 + threadIdx.x;  // 2 * 8 * 16 * 32 = 8192
  const int i  = id & 31;                          // pair index 0..31
  const int h  = (id >> 5) & 15;
  const int b  = (id >> 9) & 7;
  const int t  = id >> 12;                         // 0 = q, 1 = k
  float* buf = t ? kb : qb;
  const float p = (float)pos[b];
  const float inv = (float)pow(10000.0, -(double)i / 32.0); // 10000^(-2i/64)
  const float ang = p * inv;                       // fp32 product, like the ref
  const float s = sinf(ang), c = cosf(ang);
  const int idx = b * DM + h * DHD + 2 * i;
  const float x1 = buf[idx], x2 = buf[idx + 1];
  buf[idx]     = x1 * c - x2 * s;
  buf[idx + 1] = x2 * c + x1 * s;
}

// ---------------- kernel 3: flash-decode attention, split-K -------------------
__global__ __launch_bounds__(256) void k_attn(const float* __restrict__ qb,
                                              const float* __restrict__ kb,
                                              const float* __restrict__ vb,
                                              const float* __restrict__ Kp,
                                              const float* __restrict__ Vp,
                                              const float* __restrict__ mask,
                                              float* __restrict__ pm,
                                              float* __restrict__ pl,
                                              float* __restrict__ pc) {
  const int blk   = blockIdx.x;
  const int bh    = blk >> 5;          // / NSPLIT
  const int split = blk & 31;
  const int b     = bh >> 4;
  const int lane  = threadIdx.x & 63;
  const int wid   = threadIdx.x >> 6;
  const int start = split * KPS;
  const int end   = min(start + KPS, STOT);

  const float4* K4 = (const float4*)Kp + (size_t)bh * NPAST * 64;
  const float4* V4 = (const float4*)Vp + (size_t)bh * NPAST * 64;
  const float4 qv = ((const float4*)qb)[bh * 64 + lane];
  const float4 kn = ((const float4*)kb)[bh * 64 + lane];   // new token's K
  const float4 vn = ((const float4*)vb)[bh * 64 + lane];   // new token's V

  float m = -3.0e38f, l = 0.f;
  float4 ctx = make_float4(0.f, 0.f, 0.f, 0.f);

  for (int j = start + wid; j < end; j += 4) {
    const float4 kk = (j < NPAST) ? K4[(size_t)j * 64 + lane] : kn;
    float s = dot4(kk, qv);
#pragma unroll
    for (int off = 32; off > 0; off >>= 1) s += __shfl_xor(s, off, 64);
    s = s * 0.0625f + mask[b * STOT + j];     // scale = 1/sqrt(256)
    const float mn = fmaxf(m, s);
    const float corr = __expf(m - mn);        // first iter: exp(-huge) = 0
    const float p = __expf(s - mn);
    l = l * corr + p;
    const float4 vv = (j < NPAST) ? V4[(size_t)j * 64 + lane] : vn;
    ctx.x = fmaf(ctx.x, corr, p * vv.x);
    ctx.y = fmaf(ctx.y, corr, p * vv.y);
    ctx.z = fmaf(ctx.z, corr, p * vv.z);
    ctx.w = fmaf(ctx.w, corr, p * vv.w);
    m = mn;
  }

  // combine the block's 4 waves
  __shared__ float sm[4], sl[4];
  __shared__ float4 sctx[4][64];
  if (lane == 0) { sm[wid] = m; sl[wid] = l; }
  sctx[wid][lane] = ctx;
  __syncthreads();

  const float M = fmaxf(fmaxf(sm[0], sm[1]), fmaxf(sm[2], sm[3]));
  const int e = threadIdx.x;                  // 0..255
  const float* sc = (const float*)sctx;       // [4][256]
  float accv = 0.f;
#pragma unroll
  for (int w = 0; w < 4; ++w) accv += sc[w * 256 + e] * __expf(sm[w] - M);
  pc[(size_t)blk * 256 + e] = accv;
  if (threadIdx.x == 0) {
    float L = 0.f;
#pragma unroll
    for (int w = 0; w < 4; ++w) L += sl[w] * __expf(sm[w] - M);
    pm[blk] = M;
    pl[blk] = L;
  }
}

// ---------------- kernel 4: combine splits -> ctx_full ------------------------
__global__ __launch_bounds__(256) void k_comb(const float* __restrict__ pm,
                                              const float* __restrict__ pl,
                                              const float* __restrict__ pc,
                                              float* __restrict__ ctxf) {
  const int bh = blockIdx.x;
  const int e  = threadIdx.x;
  float M = -3.0e38f;
  for (int s = 0; s < NSPLIT; ++s) M = fmaxf(M, pm[bh * NSPLIT + s]);
  float L = 0.f, acc = 0.f;
  for (int s = 0; s < NSPLIT; ++s) {
    const float c = __expf(pm[bh * NSPLIT + s] - M);
    L   += pl[bh * NSPLIT + s] * c;
    acc += pc[((size_t)bh * NSPLIT + s) * 256 + e] * c;
  }
  // ctx transpose(0,2,1,3).reshape -> ctx_full[b][h*256+e] == [bh*256+e]
  ctxf[bh * 256 + e] = acc / L;
}

// ---------------- kernel 5: output projection GEMV, fp32 out ------------------
__global__ __launch_bounds__(256) void k_out(const float* __restrict__ ctxf,
                                             const float* __restrict__ Wo,
                                             float* __restrict__ out) {
  const int lane = threadIdx.x & 63;
  const int wid  = threadIdx.x >> 6;
  const int task = blockIdx.x * 4 + wid;      // 0..1023
  const int r    = task << 2;
  const float4* W4 = (const float4*)(Wo + (size_t)r * DM);
  const float4* x4 = (const float4*)ctxf;

  float a0[8], a1[8], a2[8], a3[8];
#pragma unroll
  for (int b = 0; b < 8; ++b) a0[b] = a1[b] = a2[b] = a3[b] = 0.f;

  for (int it = 0; it < 16; ++it) {
    const int c4 = it * 64 + lane;
    const float4 w0 = W4[c4];
    const float4 w1 = W4[1024 + c4];
    const float4 w2 = W4[2048 + c4];
    const float4 w3 = W4[3072 + c4];
#pragma unroll
    for (int b = 0; b < 8; ++b) {
      const float4 hv = x4[b * 1024 + c4];
      a0[b] += dot4(w0, hv);
      a1[b] += dot4(w1, hv);
      a2[b] += dot4(w2, hv);
      a3[b] += dot4(w3, hv);
    }
  }
#pragma unroll
  for (int b = 0; b < 8; ++b) {
    const float v0 = wave_sum(a0[b]);
    const float v1 = wave_sum(a1[b]);
    const float v2 = wave_sum(a2[b]);
    const float v3 = wave_sum(a3[b]);
    if (lane == b) {
      out[b * DM + r + 0] = v0;
      out[b * DM + r + 1] = v1;
      out[b * DM + r + 2] = v2;
      out[b * DM + r + 3] = v3;
    }
  }
}

extern "C" void kernel_launch(void* const* d_in, const int* in_sizes, int n_in,
                              void* d_out, int out_size, void* d_ws, size_t ws_size,
                              hipStream_t stream) {
  const float* hid  = (const float*)d_in[0];   // [8,1,4096]
  const float* Kp   = (const float*)d_in[1];   // [8,16,4096,256]
  const float* Vp   = (const float*)d_in[2];   // [8,16,4096,256]
  const float* mask = (const float*)d_in[3];   // [8,1,1,4097]
  const int*   pos  = (const int*)d_in[4];     // [8,1] (int32 on device)
  const float* Wq   = (const float*)d_in[5];   // [4096,4096]
  const float* Wk   = (const float*)d_in[6];
  const float* Wv   = (const float*)d_in[7];
  const float* Wo   = (const float*)d_in[8];

  float* ws   = (float*)d_ws;
  float* qb   = ws;                 // 32768  (B*DM)
  float* kb   = ws + 32768;         // 32768
  float* vb   = ws + 65536;         // 32768
  float* ctxf = ws + 98304;         // 32768
  float* pm   = ws + 131072;        // 4096   (B*H*NSPLIT)
  float* pl   = ws + 135168;        // 4096
  float* pc   = ws + 139264;        // 1048576 (B*H*NSPLIT*256)
                                    // total ~4.75 MB

  k_qkv <<<768, 256, 0, stream>>>(hid, Wq, Wk, Wv, qb, kb, vb);
  k_rope<<<32, 256, 0, stream>>>(qb, kb, pos);
  k_attn<<<NB * NH * NSPLIT, 256, 0, stream>>>(qb, kb, vb, Kp, Vp, mask, pm, pl, pc);
  k_comb<<<NB * NH, 256, 0, stream>>>(pm, pl, pc, ctxf);
  k_out <<<256, 256, 0, stream>>>(ctxf, Wo, (float*)d_out);
}